// Round 7
// baseline (3664.220 us; speedup 1.0000x reference)
//
#include <hip/hip_runtime.h>
#include <hip/hip_bf16.h>
#include <cstdint>
#include <cstddef>

// ---------------------------------------------------------------------------
// DisentangledMultiHeadAttention: B=8, H=2, T=2048, D=2048, C=4096
// 256x256-tile bf16 MFMA GEMM, 8 waves (2M x 4N), 32x32x16 MFMA,
// K-slab ring (4 x K=32, 128KB LDS), SINGLE barrier per slab:
//   slab p: vmcnt(8) [slab p landed, counted -- never 0 mid-loop] ; s_barrier ;
//           STAGE(p+3) ; 12x ds_read_b128 ; setprio1 ; 16 MFMA ; setprio0
// No explicit lgkmcnt: compiler emits progressive lgkmcnt(4/3/1/0) between
// ds_read and dependent MFMA (m97 behavior) -- R5/R6's explicit drains broke
// this. WAR safety: every wave's slot-p reads are lgkm-drained before its
// last MFMA(p) issue (DS completes in-order), hence before it passes
// barrier(p+1); STAGE(p+3) [slot (p-1)&3] issues only after barrier(p).
// LDS FRAGMENT-MAJOR: 1KB units, lane l reads/writes unit_base + l*16B
// (0 conflicts both sides, gld_lds-compatible).
// Fused QKV: one GEMM, B = [Wq;Wk;Wv] stacked (12288x4096), 3-way epilogue;
// v stored TRANSPOSED so PV is NT; softmax emits bf16 probs for PV.
// ---------------------------------------------------------------------------

typedef short short8_t __attribute__((ext_vector_type(8)));
typedef float f32x16  __attribute__((ext_vector_type(16)));

__device__ __forceinline__ short f2bf(float f) {
  unsigned u = __builtin_bit_cast(unsigned, f);
  u = (u + 0x7FFFu + ((u >> 16) & 1u)) >> 16;   // round-to-nearest-even
  return (short)u;
}

__device__ __forceinline__ short8_t cvt8(float4 a, float4 b) {
  short8_t r;
  r[0] = f2bf(a.x); r[1] = f2bf(a.y); r[2] = f2bf(a.z); r[3] = f2bf(a.w);
  r[4] = f2bf(b.x); r[5] = f2bf(b.y); r[6] = f2bf(b.z); r[7] = f2bf(b.w);
  return r;
}

__device__ __forceinline__ void gld_lds16(const void* g, void* l) {
  __builtin_amdgcn_global_load_lds(
      (const __attribute__((address_space(1))) void*)g,
      (__attribute__((address_space(3))) void*)l, 16, 0, 0);
}

// fp32 -> bf16 bulk convert, 8 elem/thread, grid-stride
__global__ __launch_bounds__(256)
void cvt_f32_bf16(const float* __restrict__ src, short* __restrict__ dst, int n8) {
  for (int i = blockIdx.x * blockDim.x + threadIdx.x; i < n8;
       i += gridDim.x * blockDim.x) {
    const float4* p = (const float4*)(src + (size_t)i * 8);
    float4 a = p[0], b = p[1];
    *(short8_t*)(dst + (size_t)i * 8) = cvt8(a, b);
  }
}

// MODE 0: fused QKV   A=xb(16384x4096) B=[Wq;Wk;Wv](12288x4096)  K=4096
//                     C->qb (b,h,t,d), C2->kb (b,h,t,d), C3->vtb (b,h,d,s)
// MODE 3: scores      C=f32 scale+bias -> attn (d_out)           K=2048, z
// MODE 4: PV          C=bf16 (b*T+t, h*D+d)                      K=2048, z
// MODE 5: out proj    C=f32 y (d_out)                            K=4096
template<int MODE>
__global__ __launch_bounds__(512, 2)
void gemm256(const short* __restrict__ Ag, const short* __restrict__ Bg,
             void* __restrict__ Cg, void* __restrict__ C2, void* __restrict__ C3,
             const float* __restrict__ bias) {
  constexpr int K  = (MODE == 3 || MODE == 4) ? 2048 : 4096;
  constexpr int NS = K / 32;   // K-slabs

  // ring: 4 slots x 32KB; per slot: 16 A units (1KB each), then 16 B units.
  __shared__ short lds[65536];

  const int tid = threadIdx.x;

  // T1: bijective XCD swizzle (grid divisible by 8: 3072 or 1024)
  const int bid = blockIdx.x;
  const int id  = (bid & 7) * (gridDim.x >> 3) + (bid >> 3);

  int m0, n0, z = 0;
  size_t aoff = 0, boff = 0;
  if constexpr (MODE == 3 || MODE == 4) {
    z  = id >> 6;                       // 16 batches
    m0 = ((id >> 3) & 7) << 8;          // 8 m-tiles
    n0 = (id & 7) << 8;                 // 8 n-tiles
    aoff = boff = (size_t)z << 22;
  } else if constexpr (MODE == 0) {
    m0 = (id / 48) << 8;                // 64 m-tiles
    n0 = (id % 48) << 8;                // 48 n-tiles (12288 cols)
  } else {
    m0 = (id >> 4) << 8;                // 64 m-tiles
    n0 = (id & 15) << 8;                // 16 n-tiles
  }

  const int l = tid & 63;
  const int w = tid >> 6;               // wave id 0..7

  // ---- staging (frag-major, 32x32x16 operand layout):
  //      A unit (m,kh) = rows [m*32,m*32+32) x k [kh*16,kh*16+16);
  //      lane l holds (row m*32+(l&31), k kh*16+(l>>5)*8 .. +7) = 16B.
  //      Wave w stages A units {2w,2w+1} (m=w, kh=0/1), B likewise (n=w).
  const int srow = l & 31;
  const int sk8  = (l >> 5) * 8;
  const short* ApS0 = Ag + aoff + (size_t)(m0 + w * 32 + srow) * K + sk8;
  const short* ApS1 = ApS0 + 16;
  const short* BpS0 = Bg + boff + (size_t)(n0 + w * 32 + srow) * K + sk8;
  const short* BpS1 = BpS0 + 16;
  short* lA0 = &lds[(2 * w + 0) * 512 + l * 8];
  short* lA1 = &lds[(2 * w + 1) * 512 + l * 8];
  short* lB0 = &lds[8192 + (2 * w + 0) * 512 + l * 8];
  short* lB1 = &lds[8192 + (2 * w + 1) * 512 + l * 8];

  auto STAGE = [&](int t) {
    const int s = (t & 3) << 14;
    const int k = t * 32;
    gld_lds16(ApS0 + k, lA0 + s);
    gld_lds16(ApS1 + k, lA1 + s);
    gld_lds16(BpS0 + k, lB0 + s);
    gld_lds16(BpS1 + k, lB1 + s);
  };

  // ---- fragment read bases (conflict-free: unit base + l*16B) ----
  const int wmF = (w >> 2) * 4;         // m-frag base (0 or 4)
  const int wnF = (w & 3) * 2;          // n-frag base (0,2,4,6)
  const int l8  = l * 8;

  f32x16 acc[4][2] = {};

  STAGE(0); STAGE(1); STAGE(2);

  for (int p = 0; p < NS; ++p) {
    // counted vmcnt BEFORE barrier: own slab-p loads landed; barrier makes
    // every wave's slab-p loads visible.
    if (p + 2 < NS)      asm volatile("s_waitcnt vmcnt(8)" ::: "memory");
    else if (p + 1 < NS) asm volatile("s_waitcnt vmcnt(4)" ::: "memory");
    else                 asm volatile("s_waitcnt vmcnt(0)" ::: "memory");
    __builtin_amdgcn_s_barrier();

    if (p + 3 < NS) STAGE(p + 3);       // slot (p-1)&3: WAR-safe (see header)

    const int slot = (p & 3) << 14;
    short8_t A[4][2], B[2][2];
#pragma unroll
    for (int i = 0; i < 4; ++i)
#pragma unroll
      for (int kh = 0; kh < 2; ++kh)
        A[i][kh] = *(const short8_t*)&lds[slot + ((wmF + i) * 2 + kh) * 512 + l8];
#pragma unroll
    for (int j = 0; j < 2; ++j)
#pragma unroll
      for (int kh = 0; kh < 2; ++kh)
        B[j][kh] = *(const short8_t*)&lds[slot + 8192 + ((wnF + j) * 2 + kh) * 512 + l8];

    __builtin_amdgcn_s_setprio(1);
#pragma unroll
    for (int kh = 0; kh < 2; ++kh)
#pragma unroll
      for (int i = 0; i < 4; ++i)
#pragma unroll
        for (int j = 0; j < 2; ++j)
          acc[i][j] = __builtin_amdgcn_mfma_f32_32x32x16_bf16(A[i][kh], B[j][kh], acc[i][j], 0, 0, 0);
    __builtin_amdgcn_s_setprio(0);
  }

  // ---- epilogue: 32x32 C/D layout col=lane&31, row=(r&3)+8*(r>>2)+4*(l>>5)
  const int col = l & 31;
  const int rhi = (l >> 5) * 4;
#pragma unroll
  for (int i = 0; i < 4; ++i) {
#pragma unroll
    for (int j = 0; j < 2; ++j) {
#pragma unroll
      for (int r = 0; r < 16; ++r) {
        const int row = (r & 3) + 8 * (r >> 2) + rhi;
        const int gm  = m0 + (w >> 2) * 128 + i * 32 + row;
        const int gn  = n0 + (w & 3) * 64 + j * 32 + col;
        const float v = acc[i][j][r];
        if constexpr (MODE == 0) {
          const int wsel = gn >> 12;          // 0:q 1:k 2:v
          const int c    = gn & 4095;
          const int bh   = ((gm >> 11) << 1) + (c >> 11);
          if (wsel == 2) {
            ((short*)C3)[((size_t)bh << 22) + ((size_t)(c & 2047) << 11) + (gm & 2047)] = f2bf(v);
          } else {
            short* dst = wsel ? (short*)C2 : (short*)Cg;
            dst[((size_t)bh << 22) + ((size_t)(gm & 2047) << 11) + (c & 2047)] = f2bf(v);
          }
        } else if constexpr (MODE == 3) {
          float* dst = (float*)Cg;
          const float sv = v * 0.022097086912079608f + bias[((z & 1) << 11) + gn];
          dst[((size_t)z << 22) + ((size_t)gm << 11) + gn] = sv;
        } else if constexpr (MODE == 4) {
          short* dst = (short*)Cg;
          const size_t orow = ((size_t)(z >> 1) << 11) + gm;
          dst[(orow << 12) + ((size_t)(z & 1) << 11) + gn] = f2bf(v);
        } else {
          float* dst = (float*)Cg;
          dst[(size_t)gm * 4096 + gn] = v;
        }
      }
    }
  }
}

// row softmax in place (fp32, 2048 wide) + bf16 copy for the PV GEMM
__global__ __launch_bounds__(256)
void softmax_rows(float* __restrict__ attn, short* __restrict__ outb) {
  float* row  = attn + ((size_t)blockIdx.x << 11);
  short* rowb = outb + ((size_t)blockIdx.x << 11);
  const int tid = threadIdx.x;

  float4 v0 = *(const float4*)(row + tid * 8);
  float4 v1 = *(const float4*)(row + tid * 8 + 4);

  float m = fmaxf(fmaxf(fmaxf(v0.x, v0.y), fmaxf(v0.z, v0.w)),
                  fmaxf(fmaxf(v1.x, v1.y), fmaxf(v1.z, v1.w)));
#pragma unroll
  for (int off = 1; off < 64; off <<= 1) m = fmaxf(m, __shfl_xor(m, off));

  __shared__ float redm[4];
  __shared__ float reds[4];
  if ((tid & 63) == 0) redm[tid >> 6] = m;
  __syncthreads();
  m = fmaxf(fmaxf(redm[0], redm[1]), fmaxf(redm[2], redm[3]));

  float e[8];
  e[0] = expf(v0.x - m); e[1] = expf(v0.y - m); e[2] = expf(v0.z - m); e[3] = expf(v0.w - m);
  e[4] = expf(v1.x - m); e[5] = expf(v1.y - m); e[6] = expf(v1.z - m); e[7] = expf(v1.w - m);
  float s = 0.f;
#pragma unroll
  for (int i = 0; i < 8; ++i) s += e[i];
#pragma unroll
  for (int off = 1; off < 64; off <<= 1) s += __shfl_xor(s, off);
  if ((tid & 63) == 0) reds[tid >> 6] = s;
  __syncthreads();
  s = reds[0] + reds[1] + reds[2] + reds[3];

  const float inv = 1.0f / s;
  float4 o0, o1;
  o0.x = e[0] * inv; o0.y = e[1] * inv; o0.z = e[2] * inv; o0.w = e[3] * inv;
  o1.x = e[4] * inv; o1.y = e[5] * inv; o1.z = e[6] * inv; o1.w = e[7] * inv;
  *(float4*)(row + tid * 8)     = o0;
  *(float4*)(row + tid * 8 + 4) = o1;
  *(short8_t*)(rowb + tid * 8)  = cvt8(o0, o1);
}

extern "C" void kernel_launch(void* const* d_in, const int* in_sizes, int n_in,
                              void* d_out, int out_size, void* d_ws, size_t ws_size,
                              hipStream_t stream) {
  const float* x  = (const float*)d_in[0];
  const float* Wq = (const float*)d_in[1];
  const float* Wk = (const float*)d_in[2];
  const float* Wv = (const float*)d_in[3];
  const float* Wo = (const float*)d_in[4];
  const float* pb = (const float*)d_in[5];

  float* y_out = (float*)d_out;                       // 8*2048*4096 f32
  float* attn  = y_out + (size_t)8 * 2048 * 4096;     // 16*2048*2048 f32

  const size_t NEED = 4ull * 67108864ull * 2ull;      // 512 MB
  if (ws_size < NEED) return;
  short* buf0 = (short*)d_ws;
  short* buf1 = buf0 + 67108864;
  short* buf2 = buf1 + 67108864;
  short* buf3 = buf2 + 67108864;

  short* xb      = buf0;             // x bf16 (16384 x 4096)
  short* qb      = buf1;             // (b,h,t,d)
  short* kb      = buf2;             // (b,h,t,d)
  short* vtb     = buf3;             // (b,h,d,s)
  short* wob     = buf0;             // Wo bf16 (reuses xb after QKV)
  short* attn_bf = buf1;             // bf16 probs (reuses qb after scores)
  short* yb      = buf2;             // attn@v bf16 (reuses kb after scores)
  short* wqkv    = (short*)attn;     // [Wq;Wk;Wv] bf16 (96 MB) in d_out attn
                                     // region (dead until scores GEMM)

  const dim3 blk512(512);
  const dim3 blk(256);
  const dim3 gcv(2048);

  cvt_f32_bf16<<<gcv, blk, 0, stream>>>(x, xb, 67108864 / 8);
  cvt_f32_bf16<<<gcv, blk, 0, stream>>>(Wq, wqkv,                 16777216 / 8);
  cvt_f32_bf16<<<gcv, blk, 0, stream>>>(Wk, wqkv + 16777216,      16777216 / 8);
  cvt_f32_bf16<<<gcv, blk, 0, stream>>>(Wv, wqkv + 2 * 16777216,  16777216 / 8);

  gemm256<0><<<dim3(3072), blk512, 0, stream>>>(xb, wqkv, qb, kb, vtb, nullptr);

  cvt_f32_bf16<<<gcv, blk, 0, stream>>>(Wo, wob, 16777216 / 8);   // x dead now

  gemm256<3><<<dim3(1024), blk512, 0, stream>>>(qb, kb, attn, nullptr, nullptr, pb);
  softmax_rows<<<dim3(32768), blk, 0, stream>>>(attn, attn_bf);
  gemm256<4><<<dim3(1024), blk512, 0, stream>>>(attn_bf, vtb, yb, nullptr, nullptr, nullptr);
  gemm256<5><<<dim3(1024), blk512, 0, stream>>>(yb, wob, y_out, nullptr, nullptr, nullptr);
}

// Round 8
// 2921.634 us; speedup vs baseline: 1.2542x; 1.2542x over previous
//
#include <hip/hip_runtime.h>
#include <hip/hip_bf16.h>
#include <cstdint>
#include <cstddef>

// ---------------------------------------------------------------------------
// DisentangledMultiHeadAttention: B=8, H=2, T=2048, D=2048, C=4096
// R4 structure (best measured: 2925 us, MfmaUtil 44.5) + two changes:
//  (1) SINGLE barrier per K-slab (was 2). Proof: reads of slot (p+1)&3 at
//      phase p are lgkm-drained before MFMA(p+1) (compiler waitcnt), which
//      precedes barrier(p+2); STAGE(p+5) (the next writer of that slot)
//      issues only after barrier(p+2). RAW: vmcnt(4) before barrier(p)
//      retires slab p+1; barrier publishes across waves.
//  (2) Non-temporal loads/stores on all streaming traffic (fp32 inputs,
//      GEMM outputs, softmax fp32) to stop L3 thrash: proj FETCH was 590MB
//      vs ~160MB compulsory.
// 256x256 tile, 8 waves (2Mx4N), 16x16x32 bf16 MFMA, 4-slot K=32 LDS ring,
// register fragment double-buffer, 2-way LDS swizzle (measured 0 conflicts),
// T1 XCD swizzle, T5 setprio. v stored TRANSPOSED so PV is NT; softmax
// emits bf16 probs for PV.
// ---------------------------------------------------------------------------

typedef short short8_t __attribute__((ext_vector_type(8)));
typedef float f32x4   __attribute__((ext_vector_type(4)));

__device__ __forceinline__ short f2bf(float f) {
  unsigned u = __builtin_bit_cast(unsigned, f);
  u = (u + 0x7FFFu + ((u >> 16) & 1u)) >> 16;   // round-to-nearest-even
  return (short)u;
}

__device__ __forceinline__ short8_t cvt8(f32x4 a, f32x4 b) {
  short8_t r;
  r[0] = f2bf(a[0]); r[1] = f2bf(a[1]); r[2] = f2bf(a[2]); r[3] = f2bf(a[3]);
  r[4] = f2bf(b[0]); r[5] = f2bf(b[1]); r[6] = f2bf(b[2]); r[7] = f2bf(b[3]);
  return r;
}

__device__ __forceinline__ void gld_lds16(const void* g, void* l) {
  __builtin_amdgcn_global_load_lds(
      (const __attribute__((address_space(1))) void*)g,
      (__attribute__((address_space(3))) void*)l, 16, 0, 0);
}

// fp32 -> bf16 bulk convert; NT loads (fp32 source is dead after this)
__global__ __launch_bounds__(256)
void cvt_f32_bf16(const float* __restrict__ src, short* __restrict__ dst, int n8) {
  for (int i = blockIdx.x * blockDim.x + threadIdx.x; i < n8;
       i += gridDim.x * blockDim.x) {
    const f32x4* p = (const f32x4*)(src + (size_t)i * 8);
    f32x4 a = __builtin_nontemporal_load(p);
    f32x4 b = __builtin_nontemporal_load(p + 1);
    *(short8_t*)(dst + (size_t)i * 8) = cvt8(a, b);
  }
}

// MODE 0: q/k proj  C=bf16 (b,h,t,d)                 K=4096
// MODE 2: v proj    C=bf16 (b,h,d,s) [transposed]    K=4096
// MODE 3: scores    C=f32 scale+bias -> attn (d_out) K=2048, batched z
// MODE 4: PV        C=bf16 (b*T+t, h*D+d)            K=2048, batched z
// MODE 5: out proj  C=f32 y (d_out)                  K=4096
template<int MODE>
__global__ __launch_bounds__(512, 2)
void gemm256(const short* __restrict__ Ag, const short* __restrict__ Bg,
             void* __restrict__ Cg, const float* __restrict__ bias) {
  constexpr int K  = (MODE == 3 || MODE == 4) ? 2048 : 4096;
  constexpr int NS = K / 32;   // K-slabs (even)

  __shared__ short lds[65536];  // 4 slots x (A 8192 + B 8192 shorts) = 128KB

  const int tid = threadIdx.x;

  // T1: bijective XCD swizzle (gridDim.x = 1024, divisible by 8)
  const int bid = blockIdx.x;
  const int id  = (bid & 7) * (gridDim.x >> 3) + (bid >> 3);

  int m0, n0, z = 0;
  size_t aoff = 0, boff = 0;
  if constexpr (MODE == 3 || MODE == 4) {
    z  = id >> 6;                       // 16 batches
    m0 = ((id >> 3) & 7) << 8;          // 8 m-tiles
    n0 = (id & 7) << 8;                 // 8 n-tiles
    aoff = boff = (size_t)z << 22;
  } else {
    m0 = (id >> 4) << 8;                // 64 m-tiles
    n0 = (id & 15) << 8;                // 16 n-tiles (n fastest: A-panel reuse)
  }

  // ---- staging: slab = 1024 chunks of 16B; thread does chunks tid, tid+512
  //      per operand. chunk c -> row c>>2, phys slot c&3; global source slot
  //      = phys ^ ((row>>1)&3)  [inverse swizzle, both-sides rule].
  const int r0 = tid >> 2;
  const int qs = ((tid & 3) ^ ((r0 >> 1) & 3)) << 3;
  const short* Ap0 = Ag + aoff + (size_t)(m0 + r0) * K + qs;
  const short* Ap1 = Ap0 + (size_t)128 * K;
  const short* Bp0 = Bg + boff + (size_t)(n0 + r0) * K + qs;
  const short* Bp1 = Bp0 + (size_t)128 * K;
  short* la0 = &lds[0]    + tid * 8;
  short* la1 = la0 + 4096;
  short* lb0 = &lds[8192] + tid * 8;
  short* lb1 = lb0 + 4096;

  auto STAGE = [&](int t) {
    const int s = (t & 3) * 16384;
    const int k = t * 32;
    gld_lds16(Ap0 + k, la0 + s);
    gld_lds16(Ap1 + k, la1 + s);
    gld_lds16(Bp0 + k, lb0 + s);
    gld_lds16(Bp1 + k, lb1 + s);
  };

  // ---- fragment read setup (2-way-conflict swizzled) ----
  const int l  = tid & 63;
  const int fr = l & 15;
  const int kq = l >> 4;
  const int wm = (tid >> 8) << 7;         // wave m offset: 0 / 128
  const int wn = ((tid >> 6) & 3) << 6;   // wave n offset: 0/64/128/192
  const int slotP = (kq ^ ((fr >> 1) & 3)) << 3;
  const int aB = (wm + fr) * 32 + slotP;
  const int bB = 8192 + (wn + fr) * 32 + slotP;

  f32x4 acc[8][4] = {};
  short8_t fA[8], fB[4], gA[8], gB[4];

  // phase p (single barrier): vmcnt(4) [slab p+1 landed]; barrier;
  // STAGE(p+3) [slot (p-1)&3, WAR-safe]; read slab p+1 frags -> nxt regs
  // (overlaps MFMA); MFMA slab p from cur regs.
  auto phase = [&](int p, short8_t (&cA)[8], short8_t (&cB)[4],
                   short8_t (&nA)[8], short8_t (&nB)[4]) {
    if (p + 2 < NS) {
      asm volatile("s_waitcnt vmcnt(4)" ::: "memory");   // slab p+1 landed
    } else {
      asm volatile("s_waitcnt vmcnt(0)" ::: "memory");
    }
    __builtin_amdgcn_s_barrier();
    if (p + 3 < NS) STAGE(p + 3);
    if (p + 1 < NS) {
      const short* sl = &lds[((p + 1) & 3) * 16384];
#pragma unroll
      for (int m = 0; m < 8; ++m) nA[m] = *(const short8_t*)&sl[aB + m * 512];
#pragma unroll
      for (int n = 0; n < 4; ++n) nB[n] = *(const short8_t*)&sl[bB + n * 512];
    }
    __builtin_amdgcn_s_setprio(1);
#pragma unroll
    for (int m = 0; m < 8; ++m)
#pragma unroll
      for (int n = 0; n < 4; ++n)
        acc[m][n] = __builtin_amdgcn_mfma_f32_16x16x32_bf16(cA[m], cB[n], acc[m][n], 0, 0, 0);
    __builtin_amdgcn_s_setprio(0);
  };

  STAGE(0); STAGE(1); STAGE(2);
  asm volatile("s_waitcnt vmcnt(8)" ::: "memory");   // slab 0 landed
  __builtin_amdgcn_s_barrier();
  {
    const short* sl = &lds[0];
#pragma unroll
    for (int m = 0; m < 8; ++m) fA[m] = *(const short8_t*)&sl[aB + m * 512];
#pragma unroll
    for (int n = 0; n < 4; ++n) fB[n] = *(const short8_t*)&sl[bB + n * 512];
  }

  for (int p = 0; p < NS; p += 2) {
    phase(p,     fA, fB, gA, gB);
    phase(p + 1, gA, gB, fA, fB);
  }

  // ---- epilogue (all outputs NT: streaming, L3-preserving) ----
#pragma unroll
  for (int m = 0; m < 8; ++m) {
#pragma unroll
    for (int n = 0; n < 4; ++n) {
#pragma unroll
      for (int r = 0; r < 4; ++r) {
        const int gm = m0 + wm + m * 16 + kq * 4 + r;
        const int gn = n0 + wn + n * 16 + fr;
        const float v = acc[m][n][r];
        if constexpr (MODE == 0) {
          short* dst = (short*)Cg;
          const int bh = ((gm >> 11) << 1) + (gn >> 11);
          __builtin_nontemporal_store(f2bf(v),
            &dst[((size_t)bh << 22) + ((size_t)(gm & 2047) << 11) + (gn & 2047)]);
        } else if constexpr (MODE == 2) {
          short* dst = (short*)Cg;
          const int bh = ((gm >> 11) << 1) + (gn >> 11);
          __builtin_nontemporal_store(f2bf(v),
            &dst[((size_t)bh << 22) + ((size_t)(gn & 2047) << 11) + (gm & 2047)]);
        } else if constexpr (MODE == 3) {
          float* dst = (float*)Cg;
          const float sv = v * 0.022097086912079608f + bias[((z & 1) << 11) + gn];
          __builtin_nontemporal_store(sv,
            &dst[((size_t)z << 22) + ((size_t)gm << 11) + gn]);
        } else if constexpr (MODE == 4) {
          short* dst = (short*)Cg;
          const size_t row = ((size_t)(z >> 1) << 11) + gm;
          __builtin_nontemporal_store(f2bf(v),
            &dst[(row << 12) + ((size_t)(z & 1) << 11) + gn]);
        } else {
          float* dst = (float*)Cg;
          __builtin_nontemporal_store(v, &dst[(size_t)gm * 4096 + gn]);
        }
      }
    }
  }
}

// row softmax in place (fp32, 2048 wide) + bf16 copy for the PV GEMM.
// fp32 in/out is streaming (NT); bf16 copy stays cached (PV reads it next).
__global__ __launch_bounds__(256)
void softmax_rows(float* __restrict__ attn, short* __restrict__ outb) {
  float* row  = attn + ((size_t)blockIdx.x << 11);
  short* rowb = outb + ((size_t)blockIdx.x << 11);
  const int tid = threadIdx.x;

  f32x4 v0 = __builtin_nontemporal_load((const f32x4*)(row + tid * 8));
  f32x4 v1 = __builtin_nontemporal_load((const f32x4*)(row + tid * 8 + 4));

  float m = fmaxf(fmaxf(fmaxf(v0[0], v0[1]), fmaxf(v0[2], v0[3])),
                  fmaxf(fmaxf(v1[0], v1[1]), fmaxf(v1[2], v1[3])));
#pragma unroll
  for (int off = 1; off < 64; off <<= 1) m = fmaxf(m, __shfl_xor(m, off));

  __shared__ float redm[4];
  __shared__ float reds[4];
  if ((tid & 63) == 0) redm[tid >> 6] = m;
  __syncthreads();
  m = fmaxf(fmaxf(redm[0], redm[1]), fmaxf(redm[2], redm[3]));

  float e[8];
#pragma unroll
  for (int i = 0; i < 4; ++i) e[i]     = expf(v0[i] - m);
#pragma unroll
  for (int i = 0; i < 4; ++i) e[4 + i] = expf(v1[i] - m);
  float s = 0.f;
#pragma unroll
  for (int i = 0; i < 8; ++i) s += e[i];
#pragma unroll
  for (int off = 1; off < 64; off <<= 1) s += __shfl_xor(s, off);
  if ((tid & 63) == 0) reds[tid >> 6] = s;
  __syncthreads();
  s = reds[0] + reds[1] + reds[2] + reds[3];

  const float inv = 1.0f / s;
  f32x4 o0, o1;
#pragma unroll
  for (int i = 0; i < 4; ++i) { o0[i] = e[i] * inv; o1[i] = e[4 + i] * inv; }
  __builtin_nontemporal_store(o0, (f32x4*)(row + tid * 8));
  __builtin_nontemporal_store(o1, (f32x4*)(row + tid * 8 + 4));
  *(short8_t*)(rowb + tid * 8) = cvt8(o0, o1);
}

extern "C" void kernel_launch(void* const* d_in, const int* in_sizes, int n_in,
                              void* d_out, int out_size, void* d_ws, size_t ws_size,
                              hipStream_t stream) {
  const float* x  = (const float*)d_in[0];
  const float* Wq = (const float*)d_in[1];
  const float* Wk = (const float*)d_in[2];
  const float* Wv = (const float*)d_in[3];
  const float* Wo = (const float*)d_in[4];
  const float* pb = (const float*)d_in[5];

  float* y_out = (float*)d_out;                       // 8*2048*4096 f32
  float* attn  = y_out + (size_t)8 * 2048 * 4096;     // 16*2048*2048 f32

  const size_t NEED = 4ull * 67108864ull * 2ull;      // 512 MB
  if (ws_size < NEED) return;
  short* buf0 = (short*)d_ws;
  short* buf1 = buf0 + 67108864;
  short* buf2 = buf1 + 67108864;
  short* buf3 = buf2 + 67108864;

  short* xb      = buf0;             // x bf16 (16384 x 4096)
  short* qb      = buf1;             // (b,h,t,d)
  short* kb      = buf2;             // (b,h,t,d)
  short* vtb     = buf3;             // (b,h,d,s)
  short* wob     = buf0;             // Wo bf16 (reuses xb after projections)
  short* attn_bf = buf1;             // bf16 probs (reuses qb after scores)
  short* yb      = buf2;             // attn@v bf16 (reuses kb after scores)
  short* wb      = (short*)attn;     // W staging in d_out attn region
                                     // (dead until scores GEMM writes it)

  const dim3 blk512(512);
  const dim3 blk(256);
  const dim3 gcv(2048);
  const dim3 g1k(1024);

  cvt_f32_bf16<<<gcv, blk, 0, stream>>>(x, xb, 67108864 / 8);

  cvt_f32_bf16<<<gcv, blk, 0, stream>>>(Wq, wb, 16777216 / 8);
  gemm256<0><<<g1k, blk512, 0, stream>>>(xb, wb, qb, nullptr);
  cvt_f32_bf16<<<gcv, blk, 0, stream>>>(Wk, wb, 16777216 / 8);
  gemm256<0><<<g1k, blk512, 0, stream>>>(xb, wb, kb, nullptr);
  cvt_f32_bf16<<<gcv, blk, 0, stream>>>(Wv, wb, 16777216 / 8);
  gemm256<2><<<g1k, blk512, 0, stream>>>(xb, wb, vtb, nullptr);

  cvt_f32_bf16<<<gcv, blk, 0, stream>>>(Wo, wob, 16777216 / 8);  // x dead now

  gemm256<3><<<g1k, blk512, 0, stream>>>(qb, kb, attn, pb);
  softmax_rows<<<dim3(32768), blk, 0, stream>>>(attn, attn_bf);
  gemm256<4><<<g1k, blk512, 0, stream>>>(attn_bf, vtb, yb, nullptr);
  gemm256<5><<<g1k, blk512, 0, stream>>>(yb, wob, y_out, nullptr);
}